// Round 11
// baseline (395.880 us; speedup 1.0000x reference)
//
#include <hip/hip_runtime.h>
#include <hip/hip_bf16.h>

#define N_ATOMS 200000
#define N_NBR 10
#define N_MOLS 8000
#define HID 128
#define FDIM 151
#define FEAT 200
#define DFF 512
#define FFN_H 256
#define TASKS 12
#define KX 279      // FDIM + HID
#define K1P 288     // KX padded to multiple of 32
#define XSB 296     // Xs row stride (bf16), padded
#define HSB 256     // Hs row elems (XOR-block-swizzled, no pad)
#define FS 132      // Fs row stride (f32)
#define KM 328      // HID + FEAT
#define K3 352      // KM padded to multiple of 32
#define MS 360      // LDS stride for molcat tile
#define MT 64       // atoms M-tile (3125 blocks exactly)
#define SMEM_ATOMS (MT * XSB * 2 + MT * HSB * 2)   // 37888 + 32768 = 70656 B

typedef __hip_bfloat16 bf16;
typedef __attribute__((ext_vector_type(8))) __bf16 bf16x8;
typedef __attribute__((ext_vector_type(4))) float f32x4;
typedef __attribute__((ext_vector_type(16))) float f32x16;

__device__ __forceinline__ float bf2f(bf16 x) { return __bfloat162float(x); }
__device__ __forceinline__ float blo(unsigned w) { union { unsigned u; float f; } c; c.u = w << 16; return c.f; }
__device__ __forceinline__ float bhi(unsigned w) { union { unsigned u; float f; } c; c.u = w & 0xFFFF0000u; return c.f; }

// Hs swizzle: row stride 512B is 0 mod 32 banks -> XOR the 16B-block index with
// (row & 15). Bijective (32 blocks/row), applied identically on write and read.
__device__ __forceinline__ int hswz(int r, int e) {
  return r * HSB + ((e & 7) | ((((e >> 3) ^ (r & 15)) & 31) << 3));
}

// ---------------- weight prep: transpose + bf16 + K-pad (X layout: [aggr | f_atoms]) ----------------
__global__ void prep_weights_kernel(const float* __restrict__ W1,
                                    const float* __restrict__ W2,
                                    const float* __restrict__ Wf1,
                                    bf16* __restrict__ W1bT,
                                    bf16* __restrict__ W2bT,
                                    bf16* __restrict__ Wf1bT) {
  int idx = blockIdx.x * 256 + threadIdx.x;
  if (idx < DFF * K1P) {                       // W1bT[n][k'], 512x288; k'<128 -> aggr, else f_atoms
    int n = idx / K1P, k = idx - n * K1P;
    float v;
    if (k < HID)      v = W1[(size_t)(FDIM + k) * DFF + n];
    else if (k < KX)  v = W1[(size_t)(k - HID) * DFF + n];
    else              v = 0.f;
    W1bT[idx] = __float2bfloat16(v);
    return;
  }
  idx -= DFF * K1P;
  if (idx < HID * DFF) {                       // W2bT[n][k] = W2[k][n], 128x512
    int n = idx / DFF, k = idx - n * DFF;
    W2bT[idx] = __float2bfloat16(W2[(size_t)k * HID + n]);
    return;
  }
  idx -= HID * DFF;
  if (idx < FFN_H * K3) {                      // Wf1bT[n][k] = Wf1[k][n], 256x352
    int n = idx / K3, k = idx - n * K3;
    float v = (k < KM) ? Wf1[(size_t)k * FFN_H + n] : 0.f;
    Wf1bT[idx] = __float2bfloat16(v);
  }
}

// ---------------- neighbor gather-sum directly from f32 atom_output (L3-resident) ----------------
__global__ __launch_bounds__(256)
void gather_kernel(const float* __restrict__ ao,
                   const int* __restrict__ a2a,
                   bf16* __restrict__ aggr) {
  const int gid = blockIdx.x * 256 + threadIdx.x;   // exactly N_ATOMS*16 threads
  const int atom = gid >> 4, c8 = gid & 15;
  int idxs[N_NBR];
#pragma unroll
  for (int j = 0; j < N_NBR; ++j) idxs[j] = a2a[atom * N_NBR + j];
  float s[8];
#pragma unroll
  for (int e = 0; e < 8; ++e) s[e] = 0.f;
#pragma unroll
  for (int j = 0; j < N_NBR; ++j) {
    const float* p = &ao[(size_t)idxs[j] * HID + c8 * 8];
    const float4 v0 = *(const float4*)p;
    const float4 v1 = *(const float4*)(p + 4);
    s[0] += v0.x; s[1] += v0.y; s[2] += v0.z; s[3] += v0.w;
    s[4] += v1.x; s[5] += v1.y; s[6] += v1.z; s[7] += v1.w;
  }
  union { bf16 h[8]; uint4 u; } pk;
#pragma unroll
  for (int e = 0; e < 8; ++e) pk.h[e] = __float2bfloat16(s[e]);
  *(uint4*)&aggr[(size_t)atom * HID + c8 * 8] = pk.u;
}

// ---------------- fused GEMM1(relu) + GEMM2 + LayerNorm, 32x32x16, 2-phase GEMM2 ----------------
// MT=64, all-M wave tiling. GEMM1 single sweep kk-outer (X read ONCE, 36 b128/wave,
// acc1[2][2]=64 regs, 4 indep chains). Hs is 256-wide so ALL 8 waves write epi each
// phase; GEMM2 = 2 phases x 16 MFMA. 5 barriers total (vs R10's 9).
__global__ __launch_bounds__(512, 4)
void atoms_kernel(const bf16* __restrict__ aggr,
                  const float* __restrict__ f_atoms,
                  const bf16* __restrict__ W1bT,
                  const float* __restrict__ b1,
                  const bf16* __restrict__ W2bT,
                  const float* __restrict__ b2,
                  const float* __restrict__ gamma,
                  const float* __restrict__ beta,
                  bf16* __restrict__ atom_emb) {
  extern __shared__ char smem[];
  bf16* Xs = (bf16*)smem;                  // [MT][XSB] cols: 0..127 aggr, 128..278 fa, 279..287 pad
  bf16* Hs = (bf16*)(smem + MT * XSB * 2); // [MT][HSB] one 256-wide H chunk (swizzled)
  float* Fs = (float*)smem;                // [MT][FS] f32 overlay (Xs dead after GEMM1)

  const int tid = threadIdx.x;
  const int m0 = blockIdx.x * MT;
  const int lane = tid & 63;
  const int w = tid >> 6;
  const int l31 = lane & 31;
  const int lh = lane >> 5;       // k-half

  // ---- stage aggr -> Xs[:, 0:128]  (1024 uint4)
  {
    int q = tid;
#pragma unroll
    for (int p = 0; p < 2; ++p) {
      const int r = q >> 4, c8 = q & 15;
      *(uint4*)&Xs[r * XSB + c8 * 8] = *(const uint4*)&aggr[(size_t)(m0 + r) * HID + c8 * 8];
      q += 512;
    }
  }
  // ---- stage f_atoms -> Xs[:, 128:280] as (row, 16B-block) units: 2 float4 -> pack -> 1 b128
  {
    const float* fb = &f_atoms[(size_t)m0 * FDIM];
    int u = tid;
#pragma unroll
    for (int p = 0; p < 3; ++p) {
      if (p < 2 || u < MT * 19) {
        const int row = u / 19, o = u - row * 19;
        const float* src = &fb[row * FDIM + o * 8];
        float vf[8];
        if (o < 18) {
          const float4 va = *(const float4*)src;
          const float4 vb = *(const float4*)(src + 4);
          vf[0] = va.x; vf[1] = va.y; vf[2] = va.z; vf[3] = va.w;
          vf[4] = vb.x; vf[5] = vb.y; vf[6] = vb.z; vf[7] = vb.w;
        } else {            // elems 144..150 + zero pad (col 279)
          const float4 va = *(const float4*)src;
          vf[0] = va.x; vf[1] = va.y; vf[2] = va.z; vf[3] = va.w;
          vf[4] = src[4]; vf[5] = src[5]; vf[6] = src[6]; vf[7] = 0.f;
        }
        union { bf16 h[8]; uint4 q4; } pk;
#pragma unroll
        for (int e = 0; e < 8; ++e) pk.h[e] = __float2bfloat16(vf[e]);
        *(uint4*)&Xs[row * XSB + HID + o * 8] = pk.q4;
      }
      u += 512;
    }
  }
  // ---- zero K-pad cols 280..287 (one uint4 per row)
  if (tid < MT) {
    const uint4 z = {0u, 0u, 0u, 0u};
    *(uint4*)&Xs[tid * XSB + 280] = z;
  }
  __syncthreads();   // (1) Xs ready

  // ---- GEMM1: single sweep, kk-outer over K=288 (18 steps of k=16)
  // wave w owns n-tiles {w*32 (t=0), 256+w*32 (t=1)}; D[n][m] via mfma(Wfrag, Xfrag)
  f32x16 acc1[2][2];
#pragma unroll
  for (int t = 0; t < 2; ++t)
#pragma unroll
    for (int mt = 0; mt < 2; ++mt) acc1[t][mt] = (f32x16)0.f;
  {
    const bf16* w1p0 = &W1bT[(size_t)(w * 32 + l31) * K1P + lh * 8];
    const bf16* w1p1 = w1p0 + (size_t)256 * K1P;
    __builtin_amdgcn_s_setprio(1);
#pragma unroll 6
    for (int kk = 0; kk < 18; ++kk) {
      const bf16x8 b0 = *(const bf16x8*)&w1p0[kk * 16];
      const bf16x8 b1f = *(const bf16x8*)&w1p1[kk * 16];
      const bf16x8 a0 = *(const bf16x8*)&Xs[l31 * XSB + kk * 16 + lh * 8];
      const bf16x8 a1 = *(const bf16x8*)&Xs[(32 + l31) * XSB + kk * 16 + lh * 8];
      acc1[0][0] = __builtin_amdgcn_mfma_f32_32x32x16_bf16(b0, a0, acc1[0][0], 0, 0, 0);
      acc1[0][1] = __builtin_amdgcn_mfma_f32_32x32x16_bf16(b0, a1, acc1[0][1], 0, 0, 0);
      acc1[1][0] = __builtin_amdgcn_mfma_f32_32x32x16_bf16(b1f, a0, acc1[1][0], 0, 0, 0);
      acc1[1][1] = __builtin_amdgcn_mfma_f32_32x32x16_bf16(b1f, a1, acc1[1][1], 0, 0, 0);
    }
    __builtin_amdgcn_s_setprio(0);
  }

  // ---- GEMM2 over 2 phases of 256-wide chunks; every wave writes epi each phase
  const int wm = w & 1, wq = w >> 1;
  f32x16 acc2 = (f32x16)0.f;
#pragma unroll
  for (int c = 0; c < 2; ++c) {
    // epi: wave w's t=c tile occupies chunk-local cols w*32..w*32+31
#pragma unroll
    for (int g = 0; g < 4; ++g) {
      const int nl = w * 32 + 8 * g + 4 * lh;
      const float4 bb = *(const float4*)&b1[c * 256 + nl];
      const float bbf[4] = { bb.x, bb.y, bb.z, bb.w };
#pragma unroll
      for (int mt = 0; mt < 2; ++mt) {
        union { bf16 h[4]; uint2 u2; } pk;
#pragma unroll
        for (int r4 = 0; r4 < 4; ++r4) {
          const float h = acc1[c][mt][g * 4 + r4] + bbf[r4];
          pk.h[r4] = __float2bfloat16(h > 0.f ? h : 0.f);
        }
        *(uint2*)&Hs[hswz(mt * 32 + l31, nl)] = pk.u2;
      }
    }
    __syncthreads();   // (2,4) Hs chunk ready
    {
      const bf16* w2p = &W2bT[(size_t)(wq * 32 + l31) * DFF + c * 256 + lh * 8];
      __builtin_amdgcn_s_setprio(1);
#pragma unroll
      for (int kk = 0; kk < 16; ++kk) {
        const bf16x8 wb = *(const bf16x8*)&w2p[kk * 16];
        const bf16x8 hb = *(const bf16x8*)&Hs[hswz(wm * 32 + l31, kk * 16 + lh * 8)];
        acc2 = __builtin_amdgcn_mfma_f32_32x32x16_bf16(wb, hb, acc2, 0, 0, 0);
      }
      __builtin_amdgcn_s_setprio(0);
    }
    if (c == 0) __syncthreads();   // (3) Hs reads done -> phase-1 epi may overwrite
  }

  // ---- write pre-LN f32 into Fs (overlays Xs; Xs dead since GEMM1)
#pragma unroll
  for (int g = 0; g < 4; ++g) {
    const int n2 = wq * 32 + 8 * g + 4 * lh;
    const float4 bb = *(const float4*)&b2[n2];
    float4 v;
    v.x = acc2[g * 4 + 0] + bb.x;
    v.y = acc2[g * 4 + 1] + bb.y;
    v.z = acc2[g * 4 + 2] + bb.z;
    v.w = acc2[g * 4 + 3] + bb.w;
    *(float4*)&Fs[(wm * 32 + l31) * FS + n2] = v;
  }
  __syncthreads();   // (5) Fs ready

  // ---- LayerNorm: 8 rows per wave
  const float gam0 = gamma[lane], gam1 = gamma[64 + lane];
  const float bet0 = beta[lane],  bet1 = beta[64 + lane];
#pragma unroll
  for (int i = 0; i < MT / 8; ++i) {
    const int row = w * (MT / 8) + i;
    const float x0 = Fs[row * FS + lane];
    const float x1 = Fs[row * FS + 64 + lane];
    float s = x0 + x1;
    float q = x0 * x0 + x1 * x1;
#pragma unroll
    for (int off = 32; off > 0; off >>= 1) {
      s += __shfl_xor(s, off);
      q += __shfl_xor(q, off);
    }
    const float mu = s * (1.f / 128.f);
    const float var = q * (1.f / 128.f) - mu * mu;
    const float rs = rsqrtf(var + 1e-6f);
    const int atom = m0 + row;
    atom_emb[(size_t)atom * HID + lane] =
        __float2bfloat16(gam0 * ((x0 - mu) * rs) + bet0);
    atom_emb[(size_t)atom * HID + 64 + lane] =
        __float2bfloat16(gam1 * ((x1 - mu) * rs) + bet1);
  }
}

// ---------------- segment mean + concat features -> mol_cat bf16 (16 mols/block, vectorized) ----------------
__global__ __launch_bounds__(256)
void mol_kernel(const bf16* __restrict__ atom_emb,
                const float* __restrict__ features,
                const int* __restrict__ a_scope,
                bf16* __restrict__ mol_cat) {
  const int tid = threadIdx.x;
  const int mi = tid >> 4, c8 = tid & 15;
  const int base = blockIdx.x * 16;
  const int m = base + mi;
  const int start = a_scope[2 * m];
  const int size  = a_scope[2 * m + 1];
  float s[8];
#pragma unroll
  for (int e = 0; e < 8; ++e) s[e] = 0.f;
  for (int a = 0; a < size; ++a) {
    const uint4 u = *(const uint4*)&atom_emb[(size_t)(start + a) * HID + c8 * 8];
    s[0] += blo(u.x); s[1] += bhi(u.x);
    s[2] += blo(u.y); s[3] += bhi(u.y);
    s[4] += blo(u.z); s[5] += bhi(u.z);
    s[6] += blo(u.w); s[7] += bhi(u.w);
  }
  const float inv = 1.f / (float)size;
  union { bf16 h[8]; uint4 u; } pk;
#pragma unroll
  for (int e = 0; e < 8; ++e) pk.h[e] = __float2bfloat16(s[e] * inv);
  *(uint4*)&mol_cat[(size_t)m * K3 + c8 * 8] = pk.u;
  // features f32 -> bf16 (50 float4 per mol)
  for (int q = tid; q < 16 * 50; q += 256) {
    const int mm = q / 50, qq = q - mm * 50;
    const float4 v = *(const float4*)&features[(size_t)(base + mm) * FEAT + qq * 4];
    union { bf16 h[4]; uint2 u2; } pf;
    pf.h[0] = __float2bfloat16(v.x); pf.h[1] = __float2bfloat16(v.y);
    pf.h[2] = __float2bfloat16(v.z); pf.h[3] = __float2bfloat16(v.w);
    *(uint2*)&mol_cat[(size_t)(base + mm) * K3 + HID + qq * 4] = pf.u2;
  }
  // zero pad cols 328..351
  for (int q = tid; q < 16 * (K3 - KM); q += 256) {
    const int mm = q / (K3 - KM), qq = q - mm * (K3 - KM);
    mol_cat[(size_t)(base + mm) * K3 + KM + qq] = __float2bfloat16(0.f);
  }
}

// ---------------- mol FFN layer 1: [8000 x 352] @ [352 x 256] relu ----------------
__global__ __launch_bounds__(512)
void molffn1_kernel(const bf16* __restrict__ mol_cat,
                    const bf16* __restrict__ Wf1bT,
                    const float* __restrict__ bf1,
                    bf16* __restrict__ Hf) {
  __shared__ bf16 As[64 * MS];   // 45 KB
  const int tid = threadIdx.x;
  const int m0 = blockIdx.x * 64;
  for (int idx = tid; idx < 64 * (K3 / 8); idx += 512) {
    int rr = idx / (K3 / 8), qv = idx - rr * (K3 / 8);
    *(uint4*)&As[rr * MS + qv * 8] = *(const uint4*)&mol_cat[(size_t)(m0 + rr) * K3 + qv * 8];
  }
  __syncthreads();
  const int lane = tid & 63, w = tid >> 6;
  const int lr = lane & 15, lk = lane >> 4;
  const int wn = w * 32;
  f32x4 acc[4][2];
#pragma unroll
  for (int mi = 0; mi < 4; ++mi)
#pragma unroll
    for (int ni = 0; ni < 2; ++ni) acc[mi][ni] = (f32x4)0.f;
#pragma unroll 3
  for (int kk = 0; kk < K3 / 32; ++kk) {
    bf16x8 a[4], b[2];
#pragma unroll
    for (int mi = 0; mi < 4; ++mi)
      a[mi] = *(const bf16x8*)&As[(mi * 16 + lr) * MS + kk * 32 + lk * 8];
#pragma unroll
    for (int ni = 0; ni < 2; ++ni)
      b[ni] = *(const bf16x8*)&Wf1bT[(size_t)(wn + ni * 16 + lr) * K3 + kk * 32 + lk * 8];
#pragma unroll
    for (int mi = 0; mi < 4; ++mi)
#pragma unroll
      for (int ni = 0; ni < 2; ++ni)
        acc[mi][ni] = __builtin_amdgcn_mfma_f32_16x16x32_bf16(a[mi], b[ni], acc[mi][ni], 0, 0, 0);
  }
#pragma unroll
  for (int ni = 0; ni < 2; ++ni) {
    const int n = wn + ni * 16 + lr;
    const float bias = bf1[n];
#pragma unroll
    for (int mi = 0; mi < 4; ++mi)
#pragma unroll
      for (int rr = 0; rr < 4; ++rr) {
        const int row = mi * 16 + lk * 4 + rr;
        const float h = acc[mi][ni][rr] + bias;
        Hf[(size_t)(m0 + row) * FFN_H + n] = __float2bfloat16(h > 0.f ? h : 0.f);
      }
  }
}

// ---------------- mol FFN layer 2: [8000 x 256] @ [256 x 12], Wf2 in LDS, uint4 Hf loads ----------------
__global__ __launch_bounds__(192)
void molffn2_kernel(const bf16* __restrict__ Hf,
                    const float* __restrict__ Wf2,
                    const float* __restrict__ bias2,
                    float* __restrict__ out) {
  __shared__ float Ws[FFN_H * TASKS];   // 12 KB
  const int tid = threadIdx.x;          // 192 = 16 mols x 12 tasks
  for (int i = tid; i < FFN_H * TASKS; i += 192) Ws[i] = Wf2[i];
  __syncthreads();
  const int m = blockIdx.x * 16 + tid / TASKS;
  const int t = tid % TASKS;
  float s = bias2[t];
  for (int k8 = 0; k8 < FFN_H / 8; ++k8) {
    const uint4 u = *(const uint4*)&Hf[(size_t)m * FFN_H + k8 * 8];
    const float h[8] = { blo(u.x), bhi(u.x), blo(u.y), bhi(u.y),
                         blo(u.z), bhi(u.z), blo(u.w), bhi(u.w) };
#pragma unroll
    for (int e = 0; e < 8; ++e) s += h[e] * Ws[(k8 * 8 + e) * TASKS + t];
  }
  out[(size_t)m * TASKS + t] = s;
}

extern "C" void kernel_launch(void* const* d_in, const int* in_sizes, int n_in,
                              void* d_out, int out_size, void* d_ws, size_t ws_size,
                              hipStream_t stream) {
  const float* atom_output = (const float*)d_in[0];
  const float* f_atoms     = (const float*)d_in[1];
  const float* features    = (const float*)d_in[2];
  const int*   a2a         = (const int*)d_in[3];
  const int*   a_scope     = (const int*)d_in[4];
  const float* W1   = (const float*)d_in[5];
  const float* b1   = (const float*)d_in[6];
  const float* W2   = (const float*)d_in[7];
  const float* b2   = (const float*)d_in[8];
  const float* gamma = (const float*)d_in[9];
  const float* beta  = (const float*)d_in[10];
  const float* Wf1  = (const float*)d_in[11];
  const float* bf1  = (const float*)d_in[12];
  const float* Wf2  = (const float*)d_in[13];
  const float* bf2v = (const float*)d_in[14];
  float* out = (float*)d_out;

  char* ws = (char*)d_ws;
  size_t off = 0;
  bf16* W1bT  = (bf16*)(ws + off); off += (size_t)DFF * K1P * 2;     // 294912
  bf16* W2bT  = (bf16*)(ws + off); off += (size_t)HID * DFF * 2;     // 131072
  bf16* Wf1bT = (bf16*)(ws + off); off += (size_t)FFN_H * K3 * 2;    // 180224
  bf16* atom_emb = (bf16*)(ws + off); off += (size_t)N_ATOMS * HID * 2; // 51.2 MB
  bf16* mol_cat  = (bf16*)(ws + off); off += (size_t)N_MOLS * K3 * 2;   // 5.6 MB
  bf16* Hf       = (bf16*)(ws + off); off += (size_t)N_MOLS * FFN_H * 2;// 4.1 MB
  // aggr aliases atom_emb (atoms_kernel reads its tile's rows into LDS before rewriting them)
  bf16* aggr = atom_emb;

  // 70,656 B dynamic LDS for atoms_kernel (2 blocks/CU on 160 KB)
  hipFuncSetAttribute((const void*)atoms_kernel,
                      hipFuncAttributeMaxDynamicSharedMemorySize, SMEM_ATOMS);

  hipLaunchKernelGGL(prep_weights_kernel, dim3(1184), dim3(256), 0, stream,
                     W1, W2, Wf1, W1bT, W2bT, Wf1bT);
  hipLaunchKernelGGL(gather_kernel, dim3(N_ATOMS * 16 / 256), dim3(256), 0, stream,
                     atom_output, a2a, aggr);
  hipLaunchKernelGGL(atoms_kernel, dim3(N_ATOMS / MT), dim3(512), SMEM_ATOMS, stream,
                     aggr, f_atoms,
                     W1bT, b1, W2bT, b2, gamma, beta, atom_emb);
  hipLaunchKernelGGL(mol_kernel, dim3(N_MOLS / 16), dim3(256), 0, stream,
                     atom_emb, features, a_scope, mol_cat);
  hipLaunchKernelGGL(molffn1_kernel, dim3(N_MOLS / 64), dim3(512), 0, stream,
                     mol_cat, Wf1bT, bf1, Hf);
  hipLaunchKernelGGL(molffn2_kernel, dim3(N_MOLS / 16), dim3(192), 0, stream,
                     Hf, Wf2, bf2v, out);
}

// Round 13
// 283.632 us; speedup vs baseline: 1.3958x; 1.3958x over previous
//
#include <hip/hip_runtime.h>
#include <hip/hip_bf16.h>

#define N_ATOMS 200000
#define N_NBR 10
#define N_MOLS 8000
#define HID 128
#define FDIM 151
#define FEAT 200
#define DFF 512
#define FFN_H 256
#define TASKS 12
#define KX 279      // FDIM + HID
#define K1P 288     // KX padded to multiple of 32
#define XSB 288     // Xs row elems (no pad; XOR-swizzled at 16B-block granularity)
#define HSB 128     // Hs row elems (no pad; XOR-swizzled)
#define FS 132      // LDS stride (f32) for pre-LN tile
#define KM 328      // HID + FEAT
#define K3 352      // KM padded to multiple of 32
#define MS 360      // LDS stride for molcat tile
#define MT 80       // atoms M-tile (2500 blocks exactly)
#define MI 5        // MT/16
#define SMEM_ATOMS (MT * XSB * 2 + MT * HSB * 2)   // 46080 + 20480 = 66560 B -> 2 blocks/CU

typedef __hip_bfloat16 bf16;
typedef __attribute__((ext_vector_type(8))) __bf16 bf16x8;
typedef __attribute__((ext_vector_type(4))) float f32x4;

__device__ __forceinline__ float bf2f(bf16 x) { return __bfloat162float(x); }
__device__ __forceinline__ float blo(unsigned w) { union { unsigned u; float f; } c; c.u = w << 16; return c.f; }
__device__ __forceinline__ float bhi(unsigned w) { union { unsigned u; float f; } c; c.u = w & 0xFFFF0000u; return c.f; }

// XOR swizzles (element units), same map as R9 — reads unchanged.
// 16B-block XOR across rows; last 32-elem window uses 2-bit XOR to stay in-row.
__device__ __forceinline__ int xswz(int r, int e) {
  return r * XSB + (e ^ ((e < 256 ? (r & 7) : (r & 3)) << 3));
}
__device__ __forceinline__ int hswz(int r, int e) {
  return r * HSB + (e ^ ((r & 7) << 3));
}

// ---------------- weight prep: transpose + bf16 + K-pad (X layout: [aggr | f_atoms]) ----------------
__global__ void prep_weights_kernel(const float* __restrict__ W1,
                                    const float* __restrict__ W2,
                                    const float* __restrict__ Wf1,
                                    bf16* __restrict__ W1bT,
                                    bf16* __restrict__ W2bT,
                                    bf16* __restrict__ Wf1bT) {
  int idx = blockIdx.x * 256 + threadIdx.x;
  if (idx < DFF * K1P) {                       // W1bT[n][k'], 512x288; k'<128 -> aggr, else f_atoms
    int n = idx / K1P, k = idx - n * K1P;
    float v;
    if (k < HID)      v = W1[(size_t)(FDIM + k) * DFF + n];
    else if (k < KX)  v = W1[(size_t)(k - HID) * DFF + n];
    else              v = 0.f;
    W1bT[idx] = __float2bfloat16(v);
    return;
  }
  idx -= DFF * K1P;
  if (idx < HID * DFF) {                       // W2bT[n][k] = W2[k][n], 128x512
    int n = idx / DFF, k = idx - n * DFF;
    W2bT[idx] = __float2bfloat16(W2[(size_t)k * HID + n]);
    return;
  }
  idx -= HID * DFF;
  if (idx < FFN_H * K3) {                      // Wf1bT[n][k] = Wf1[k][n], 256x352
    int n = idx / K3, k = idx - n * K3;
    float v = (k < KM) ? Wf1[(size_t)k * FFN_H + n] : 0.f;
    Wf1bT[idx] = __float2bfloat16(v);
  }
}

// ---------------- atom_output f32 -> bf16 (halves gather traffic) ----------------
__global__ void conv_ao_kernel(const float* __restrict__ ao, bf16* __restrict__ ao16) {
  const int idx = blockIdx.x * 256 + threadIdx.x;   // exactly N_ATOMS*HID/8 threads
  const float4 v0 = *(const float4*)&ao[(size_t)idx * 8];
  const float4 v1 = *(const float4*)&ao[(size_t)idx * 8 + 4];
  union { bf16 h[8]; uint4 u; } pk;
  pk.h[0] = __float2bfloat16(v0.x); pk.h[1] = __float2bfloat16(v0.y);
  pk.h[2] = __float2bfloat16(v0.z); pk.h[3] = __float2bfloat16(v0.w);
  pk.h[4] = __float2bfloat16(v1.x); pk.h[5] = __float2bfloat16(v1.y);
  pk.h[6] = __float2bfloat16(v1.z); pk.h[7] = __float2bfloat16(v1.w);
  *(uint4*)&ao16[(size_t)idx * 8] = pk.u;
}

// ---------------- standalone neighbor gather-sum: no LDS, no barriers, max occupancy ----------------
__global__ __launch_bounds__(256)
void gather_kernel(const bf16* __restrict__ ao16,
                   const int* __restrict__ a2a,
                   bf16* __restrict__ aggr) {
  const int gid = blockIdx.x * 256 + threadIdx.x;   // exactly N_ATOMS*16 threads
  const int atom = gid >> 4, c8 = gid & 15;
  int idxs[N_NBR];
#pragma unroll
  for (int j = 0; j < N_NBR; ++j) idxs[j] = a2a[atom * N_NBR + j];
  float s[8];
#pragma unroll
  for (int e = 0; e < 8; ++e) s[e] = 0.f;
#pragma unroll
  for (int j = 0; j < N_NBR; ++j) {
    const uint4 u = *(const uint4*)&ao16[(size_t)idxs[j] * HID + c8 * 8];
    s[0] += blo(u.x); s[1] += bhi(u.x);
    s[2] += blo(u.y); s[3] += bhi(u.y);
    s[4] += blo(u.z); s[5] += bhi(u.z);
    s[6] += blo(u.w); s[7] += bhi(u.w);
  }
  union { bf16 h[8]; uint4 u; } pk;
#pragma unroll
  for (int e = 0; e < 8; ++e) pk.h[e] = __float2bfloat16(s[e]);
  *(uint4*)&aggr[(size_t)atom * HID + c8 * 8] = pk.u;
}

// ---------------- fused GEMM1(relu) + GEMM2 + LayerNorm ----------------
// R9 structure (16x16x32, MT=80, all-M wave tiling, 2-pass kk-outer GEMM1,
// 4-chunk GEMM2, XOR-swizzled LDS) with PACKED b128 staging: the xswz map moves
// whole 16B blocks, so staging writes become uint4 at swizzled block indices
// while the GEMM read side stays byte-identical to R9.
__global__ __launch_bounds__(512, 4)
void atoms_kernel(const bf16* __restrict__ aggr,
                  const float* __restrict__ f_atoms,
                  const bf16* __restrict__ W1bT,
                  const float* __restrict__ b1,
                  const bf16* __restrict__ W2bT,
                  const float* __restrict__ b2,
                  const float* __restrict__ gamma,
                  const float* __restrict__ beta,
                  bf16* __restrict__ atom_emb) {
  extern __shared__ char smem[];
  bf16* Xs = (bf16*)smem;                       // [MT][XSB] swizzled
  bf16* Hs = (bf16*)(smem + MT * XSB * 2);      // [MT][HSB] swizzled
  float* Fs = (float*)smem;                     // [MT][FS] f32, overlays Xs (dead after pass 2)

  const int tid = threadIdx.x;
  const int m0 = blockIdx.x * MT;
  const int lane = tid & 63;
  const int w = tid >> 6;
  const int lr = lane & 15;
  const int lk = lane >> 4;

  // ---- stage aggr -> Xs[:, 0:128] as b128 at swizzled block index (1280 uint4)
  {
    int q = tid;
#pragma unroll
    for (int p = 0; p < 3; ++p) {
      if (p < 2 || q < MT * 16) {
        const int r = q >> 4, c8 = q & 15;
        *(uint4*)&Xs[r * XSB + ((c8 ^ (r & 7)) << 3)] =
            *(const uint4*)&aggr[(size_t)(m0 + r) * HID + c8 * 8];
      }
      q += 512;
    }
  }
  // ---- stage f_atoms -> Xs[:, 128:280] as (row, 16B-unit): 2 float4 -> pack -> 1 b128 swizzled
  {
    const float* fb = &f_atoms[(size_t)m0 * FDIM];
    int u = tid;
#pragma unroll
    for (int p = 0; p < 3; ++p) {
      if (p < 2 || u < MT * 19) {
        const int row = u / 19, o = u - row * 19;     // o = 0..18, covers cols 128..279
        const float* src = &fb[row * FDIM + o * 8];
        float vf[8];
        if (o < 18) {
          const float4 va = *(const float4*)src;
          const float4 vb = *(const float4*)(src + 4);
          vf[0] = va.x; vf[1] = va.y; vf[2] = va.z; vf[3] = va.w;
          vf[4] = vb.x; vf[5] = vb.y; vf[6] = vb.z; vf[7] = vb.w;
        } else {            // f_atoms elems 144..150 + zero (col 279)
          const float4 va = *(const float4*)src;
          vf[0] = va.x; vf[1] = va.y; vf[2] = va.z; vf[3] = va.w;
          vf[4] = src[4]; vf[5] = src[5]; vf[6] = src[6]; vf[7] = 0.f;
        }
        union { bf16 h[8]; uint4 q4; } pk;
#pragma unroll
        for (int e = 0; e < 8; ++e) pk.h[e] = __float2bfloat16(vf[e]);
        const int ob = 16 + o;                        // absolute 16B-block index 16..34
        const int obs = (ob < 32) ? (ob ^ (row & 7)) : (ob ^ (row & 3));
        *(uint4*)&Xs[row * XSB + obs * 8] = pk.q4;
      }
      u += 512;
    }
  }
  // ---- zero pad block 35 (cols 280..287), swizzled with 2-bit window (80 rows)
  if (tid < MT) {
    const uint4 z = {0u, 0u, 0u, 0u};
    *(uint4*)&Xs[tid * XSB + ((35 ^ (tid & 3)) << 3)] = z;
  }
  __syncthreads();   // Xs ready

  f32x4 acc2[MI];
#pragma unroll
  for (int mi = 0; mi < MI; ++mi) acc2[mi] = (f32x4)0.f;

  // ---- two passes, each: GEMM1 over 2 chunks (kk-outer) then 2x {epi -> Hs -> GEMM2}
#pragma unroll 1
  for (int pp = 0; pp < 2; ++pp) {
    const int c0 = pp * 2;
    f32x4 acc1[2][MI];
#pragma unroll
    for (int c = 0; c < 2; ++c)
#pragma unroll
      for (int mi = 0; mi < MI; ++mi) acc1[c][mi] = (f32x4)0.f;
    {
      const bf16* w1p = &W1bT[(size_t)(c0 * 128 + w * 16 + lr) * K1P + lk * 8];
      __builtin_amdgcn_s_setprio(1);
#pragma unroll
      for (int kk = 0; kk < K1P / 32; ++kk) {
        const bf16x8 b0 = *(const bf16x8*)&w1p[kk * 32];
        const bf16x8 b1f = *(const bf16x8*)&w1p[(size_t)128 * K1P + kk * 32];
#pragma unroll
        for (int mi = 0; mi < MI; ++mi) {
          const bf16x8 a = *(const bf16x8*)&Xs[xswz(mi * 16 + lr, kk * 32 + lk * 8)];
          acc1[0][mi] = __builtin_amdgcn_mfma_f32_16x16x32_bf16(b0, a, acc1[0][mi], 0, 0, 0);
          acc1[1][mi] = __builtin_amdgcn_mfma_f32_16x16x32_bf16(b1f, a, acc1[1][mi], 0, 0, 0);
        }
      }
      __builtin_amdgcn_s_setprio(0);
    }
#pragma unroll
    for (int c = 0; c < 2; ++c) {
      const int nc = c0 + c;
      // epi: +bias, relu, pack 4 consecutive n -> Hs (swizzled)
      {
        const float4 bb = *(const float4*)&b1[nc * 128 + w * 16 + lk * 4];
        const float bbf[4] = { bb.x, bb.y, bb.z, bb.w };
#pragma unroll
        for (int mi = 0; mi < MI; ++mi) {
          union { bf16 h[4]; uint2 u2; } pk;
#pragma unroll
          for (int r = 0; r < 4; ++r) {
            const float h = acc1[c][mi][r] + bbf[r];
            pk.h[r] = __float2bfloat16(h > 0.f ? h : 0.f);
          }
          *(uint2*)&Hs[hswz(mi * 16 + lr, w * 16 + lk * 4)] = pk.u2;
        }
      }
      __syncthreads();   // Hs chunk ready
      // GEMM2 partial: Hs[80 x 128] @ W2[128chunk x 128] -> acc2
      {
        const bf16* w2p = &W2bT[(size_t)(w * 16 + lr) * DFF + nc * 128 + lk * 8];
        __builtin_amdgcn_s_setprio(1);
#pragma unroll
        for (int kk = 0; kk < 4; ++kk) {
          const bf16x8 wb = *(const bf16x8*)&w2p[kk * 32];
#pragma unroll
          for (int mi = 0; mi < MI; ++mi) {
            const bf16x8 hb = *(const bf16x8*)&Hs[hswz(mi * 16 + lr, kk * 32 + lk * 8)];
            acc2[mi] = __builtin_amdgcn_mfma_f32_16x16x32_bf16(wb, hb, acc2[mi], 0, 0, 0);
          }
        }
        __builtin_amdgcn_s_setprio(0);
      }
      __syncthreads();   // Hs reads done -> next epi may overwrite
    }
  }

  // ---- write pre-LN f32 into Fs (overlays Xs; Xs dead after pass 2 GEMM1)
  {
    const float4 b2v = *(const float4*)&b2[w * 16 + lk * 4];
#pragma unroll
    for (int mi = 0; mi < MI; ++mi) {
      float4 v;
      v.x = acc2[mi][0] + b2v.x;
      v.y = acc2[mi][1] + b2v.y;
      v.z = acc2[mi][2] + b2v.z;
      v.w = acc2[mi][3] + b2v.w;
      *(float4*)&Fs[(mi * 16 + lr) * FS + w * 16 + lk * 4] = v;
    }
  }
  __syncthreads();   // Fs ready

  // ---- LayerNorm: 10 rows per wave (gamma/beta loaded late to shrink live ranges)
  const float gam0 = gamma[lane], gam1 = gamma[64 + lane];
  const float bet0 = beta[lane],  bet1 = beta[64 + lane];
#pragma unroll
  for (int i = 0; i < MT / 8; ++i) {
    const int row = w * (MT / 8) + i;
    const float x0 = Fs[row * FS + lane];
    const float x1 = Fs[row * FS + 64 + lane];
    float s = x0 + x1;
    float q = x0 * x0 + x1 * x1;
#pragma unroll
    for (int off = 32; off > 0; off >>= 1) {
      s += __shfl_xor(s, off);
      q += __shfl_xor(q, off);
    }
    const float mu = s * (1.f / 128.f);
    const float var = q * (1.f / 128.f) - mu * mu;
    const float rs = rsqrtf(var + 1e-6f);
    const int atom = m0 + row;
    atom_emb[(size_t)atom * HID + lane] =
        __float2bfloat16(gam0 * ((x0 - mu) * rs) + bet0);
    atom_emb[(size_t)atom * HID + 64 + lane] =
        __float2bfloat16(gam1 * ((x1 - mu) * rs) + bet1);
  }
}

// ---------------- segment mean + concat features -> mol_cat bf16 (16 mols/block, vectorized) ----------------
__global__ __launch_bounds__(256)
void mol_kernel(const bf16* __restrict__ atom_emb,
                const float* __restrict__ features,
                const int* __restrict__ a_scope,
                bf16* __restrict__ mol_cat) {
  const int tid = threadIdx.x;
  const int mi = tid >> 4, c8 = tid & 15;
  const int base = blockIdx.x * 16;
  const int m = base + mi;
  const int start = a_scope[2 * m];
  const int size  = a_scope[2 * m + 1];
  float s[8];
#pragma unroll
  for (int e = 0; e < 8; ++e) s[e] = 0.f;
  for (int a = 0; a < size; ++a) {
    const uint4 u = *(const uint4*)&atom_emb[(size_t)(start + a) * HID + c8 * 8];
    s[0] += blo(u.x); s[1] += bhi(u.x);
    s[2] += blo(u.y); s[3] += bhi(u.y);
    s[4] += blo(u.z); s[5] += bhi(u.z);
    s[6] += blo(u.w); s[7] += bhi(u.w);
  }
  const float inv = 1.f / (float)size;
  union { bf16 h[8]; uint4 u; } pk;
#pragma unroll
  for (int e = 0; e < 8; ++e) pk.h[e] = __float2bfloat16(s[e] * inv);
  *(uint4*)&mol_cat[(size_t)m * K3 + c8 * 8] = pk.u;
  // features f32 -> bf16 (50 float4 per mol)
  for (int q = tid; q < 16 * 50; q += 256) {
    const int mm = q / 50, qq = q - mm * 50;
    const float4 v = *(const float4*)&features[(size_t)(base + mm) * FEAT + qq * 4];
    union { bf16 h[4]; uint2 u2; } pf;
    pf.h[0] = __float2bfloat16(v.x); pf.h[1] = __float2bfloat16(v.y);
    pf.h[2] = __float2bfloat16(v.z); pf.h[3] = __float2bfloat16(v.w);
    *(uint2*)&mol_cat[(size_t)(base + mm) * K3 + HID + qq * 4] = pf.u2;
  }
  // zero pad cols 328..351
  for (int q = tid; q < 16 * (K3 - KM); q += 256) {
    const int mm = q / (K3 - KM), qq = q - mm * (K3 - KM);
    mol_cat[(size_t)(base + mm) * K3 + KM + qq] = __float2bfloat16(0.f);
  }
}

// ---------------- mol FFN layer 1: [8000 x 352] @ [352 x 256] relu ----------------
__global__ __launch_bounds__(512)
void molffn1_kernel(const bf16* __restrict__ mol_cat,
                    const bf16* __restrict__ Wf1bT,
                    const float* __restrict__ bf1,
                    bf16* __restrict__ Hf) {
  __shared__ bf16 As[64 * MS];   // 45 KB
  const int tid = threadIdx.x;
  const int m0 = blockIdx.x * 64;
  for (int idx = tid; idx < 64 * (K3 / 8); idx += 512) {
    int rr = idx / (K3 / 8), qv = idx - rr * (K3 / 8);
    *(uint4*)&As[rr * MS + qv * 8] = *(const uint4*)&mol_cat[(size_t)(m0 + rr) * K3 + qv * 8];
  }
  __syncthreads();
  const int lane = tid & 63, w = tid >> 6;
  const int lr = lane & 15, lk = lane >> 4;
  const int wn = w * 32;
  f32x4 acc[4][2];
#pragma unroll
  for (int mi = 0; mi < 4; ++mi)
#pragma unroll
    for (int ni = 0; ni < 2; ++ni) acc[mi][ni] = (f32x4)0.f;
#pragma unroll 3
  for (int kk = 0; kk < K3 / 32; ++kk) {
    bf16x8 a[4], b[2];
#pragma unroll
    for (int mi = 0; mi < 4; ++mi)
      a[mi] = *(const bf16x8*)&As[(mi * 16 + lr) * MS + kk * 32 + lk * 8];
#pragma unroll
    for (int ni = 0; ni < 2; ++ni)
      b[ni] = *(const bf16x8*)&Wf1bT[(size_t)(wn + ni * 16 + lr) * K3 + kk * 32 + lk * 8];
#pragma unroll
    for (int mi = 0; mi < 4; ++mi)
#pragma unroll
      for (int ni = 0; ni < 2; ++ni)
        acc[mi][ni] = __builtin_amdgcn_mfma_f32_16x16x32_bf16(a[mi], b[ni], acc[mi][ni], 0, 0, 0);
  }
#pragma unroll
  for (int ni = 0; ni < 2; ++ni) {
    const int n = wn + ni * 16 + lr;
    const float bias = bf1[n];
#pragma unroll
    for (int mi = 0; mi < 4; ++mi)
#pragma unroll
      for (int rr = 0; rr < 4; ++rr) {
        const int row = mi * 16 + lk * 4 + rr;
        const float h = acc[mi][ni][rr] + bias;
        Hf[(size_t)(m0 + row) * FFN_H + n] = __float2bfloat16(h > 0.f ? h : 0.f);
      }
  }
}

// ---------------- mol FFN layer 2: [8000 x 256] @ [256 x 12], Wf2 in LDS, uint4 Hf loads ----------------
__global__ __launch_bounds__(192)
void molffn2_kernel(const bf16* __restrict__ Hf,
                    const float* __restrict__ Wf2,
                    const float* __restrict__ bias2,
                    float* __restrict__ out) {
  __shared__ float Ws[FFN_H * TASKS];   // 12 KB
  const int tid = threadIdx.x;          // 192 = 16 mols x 12 tasks
  for (int i = tid; i < FFN_H * TASKS; i += 192) Ws[i] = Wf2[i];
  __syncthreads();
  const int m = blockIdx.x * 16 + tid / TASKS;
  const int t = tid % TASKS;
  float s = bias2[t];
  for (int k8 = 0; k8 < FFN_H / 8; ++k8) {
    const uint4 u = *(const uint4*)&Hf[(size_t)m * FFN_H + k8 * 8];
    const float h[8] = { blo(u.x), bhi(u.x), blo(u.y), bhi(u.y),
                         blo(u.z), bhi(u.z), blo(u.w), bhi(u.w) };
#pragma unroll
    for (int e = 0; e < 8; ++e) s += h[e] * Ws[(k8 * 8 + e) * TASKS + t];
  }
  out[(size_t)m * TASKS + t] = s;
}

extern "C" void kernel_launch(void* const* d_in, const int* in_sizes, int n_in,
                              void* d_out, int out_size, void* d_ws, size_t ws_size,
                              hipStream_t stream) {
  const float* atom_output = (const float*)d_in[0];
  const float* f_atoms     = (const float*)d_in[1];
  const float* features    = (const float*)d_in[2];
  const int*   a2a         = (const int*)d_in[3];
  const int*   a_scope     = (const int*)d_in[4];
  const float* W1   = (const float*)d_in[5];
  const float* b1   = (const float*)d_in[6];
  const float* W2   = (const float*)d_in[7];
  const float* b2   = (const float*)d_in[8];
  const float* gamma = (const float*)d_in[9];
  const float* beta  = (const float*)d_in[10];
  const float* Wf1  = (const float*)d_in[11];
  const float* bf1  = (const float*)d_in[12];
  const float* Wf2  = (const float*)d_in[13];
  const float* bf2v = (const float*)d_in[14];
  float* out = (float*)d_out;

  char* ws = (char*)d_ws;
  size_t off = 0;
  bf16* W1bT  = (bf16*)(ws + off); off += (size_t)DFF * K1P * 2;     // 294912
  bf16* W2bT  = (bf16*)(ws + off); off += (size_t)HID * DFF * 2;     // 131072
  bf16* Wf1bT = (bf16*)(ws + off); off += (size_t)FFN_H * K3 * 2;    // 180224
  bf16* atom_emb = (bf16*)(ws + off); off += (size_t)N_ATOMS * HID * 2; // 51.2 MB
  bf16* mol_cat  = (bf16*)(ws + off); off += (size_t)N_MOLS * K3 * 2;   // 5.6 MB
  bf16* Hf       = (bf16*)(ws + off); off += (size_t)N_MOLS * FFN_H * 2;// 4.1 MB
  bf16* ao16     = (bf16*)(ws + off); off += (size_t)N_ATOMS * HID * 2; // 51.2 MB
  // aggr aliases atom_emb (atoms_kernel reads its tile's rows into LDS before rewriting them)
  bf16* aggr = atom_emb;

  // 66,560 B dynamic LDS for atoms_kernel (2 blocks/CU on 160 KB)
  hipFuncSetAttribute((const void*)atoms_kernel,
                      hipFuncAttributeMaxDynamicSharedMemorySize, SMEM_ATOMS);

  hipLaunchKernelGGL(prep_weights_kernel, dim3(1184), dim3(256), 0, stream,
                     W1, W2, Wf1, W1bT, W2bT, Wf1bT);
  hipLaunchKernelGGL(conv_ao_kernel, dim3(N_ATOMS * HID / 8 / 256), dim3(256), 0, stream,
                     atom_output, ao16);
  hipLaunchKernelGGL(gather_kernel, dim3(N_ATOMS * 16 / 256), dim3(256), 0, stream,
                     ao16, a2a, aggr);
  hipLaunchKernelGGL(atoms_kernel, dim3(N_ATOMS / MT), dim3(512), SMEM_ATOMS, stream,
                     aggr, f_atoms,
                     W1bT, b1, W2bT, b2, gamma, beta, atom_emb);
  hipLaunchKernelGGL(mol_kernel, dim3(N_MOLS / 16), dim3(256), 0, stream,
                     atom_emb, features, a_scope, mol_cat);
  hipLaunchKernelGGL(molffn1_kernel, dim3(N_MOLS / 64), dim3(512), 0, stream,
                     mol_cat, Wf1bT, bf1, Hf);
  hipLaunchKernelGGL(molffn2_kernel, dim3(N_MOLS / 16), dim3(192), 0, stream,
                     Hf, Wf2, bf2v, out);
}